// Round 1
// baseline (1398.073 us; speedup 1.0000x reference)
//
#include <hip/hip_runtime.h>

// ---------------------------------------------------------------------------
// MultiTaskGNN: 2-layer GAT (H=4 heads, C=32) + node head + edge MLP head.
// Strategy: build CSR (by dst) once, then per layer:
//   transform: h = x@W (one wave/node, 2 ch/lane), s/d attention dots via shfl
//   aggregate: per dst node, single pass over incoming edges accumulating
//              Sum(exp(a)*h[src]) and Sum(exp(a)); divide at end (softmax is
//              shift-invariant; alpha is O(10) so no max pass needed).
// ---------------------------------------------------------------------------

__global__ void zero_int_kernel(int* p, int n) {
  int i = blockIdx.x * blockDim.x + threadIdx.x;
  if (i < n) p[i] = 0;
}

__global__ void hist_kernel(const int* __restrict__ dst, int E, int* __restrict__ cnt) {
  int i = blockIdx.x * blockDim.x + threadIdx.x;
  int stride = gridDim.x * blockDim.x;
  for (; i < E; i += stride) atomicAdd(&cnt[dst[i]], 1);
}

// Single-block exclusive scan over n counts; overwrites cnt_cursor with the
// exclusive offsets (to serve as the scatter cursor) and writes offs[0..n].
__global__ __launch_bounds__(1024) void scan_kernel(int* cnt_cursor, int* offs, int n) {
  __shared__ int wsum[16];
  __shared__ int carry;
  __shared__ int tot;
  int tid = threadIdx.x;
  int lane = tid & 63;
  int w = tid >> 6;
  if (tid == 0) carry = 0;
  __syncthreads();
  for (int base = 0; base < n; base += 1024) {
    int i = base + tid;
    int v = (i < n) ? cnt_cursor[i] : 0;
    int x = v;
#pragma unroll
    for (int d2 = 1; d2 < 64; d2 <<= 1) {
      int up = __shfl_up(x, d2);
      if (lane >= d2) x += up;
    }
    if (lane == 63) wsum[w] = x;
    __syncthreads();
    if (tid == 0) {
      int t = 0;
      for (int k = 0; k < 16; ++k) { int a = wsum[k]; wsum[k] = t; t += a; }
      tot = t;
    }
    __syncthreads();
    int excl = x - v + wsum[w] + carry;
    if (i < n) { offs[i] = excl; cnt_cursor[i] = excl; }
    __syncthreads();
    if (tid == 0) carry += tot;
    __syncthreads();
  }
  if (tid == 0) offs[n] = carry;
}

__global__ void scatter_kernel(const int* __restrict__ src, const int* __restrict__ dst, int E,
                               int* __restrict__ cursor, int* __restrict__ esrc) {
  int i = blockIdx.x * blockDim.x + threadIdx.x;
  int stride = gridDim.x * blockDim.x;
  for (; i < E; i += stride) {
    int p = atomicAdd(&cursor[dst[i]], 1);
    esrc[p] = src[i];
  }
}

// One wave per node. lane l handles flat channels f=l and f=l+64 of the 128
// (H*C) outputs. Computes h = x@W, plus s[n,h] = sum_c h*a_src, d likewise.
template <int K>
__global__ void transform_kernel(const float* __restrict__ xin, const float* __restrict__ W,
                                 const float* __restrict__ a_src, const float* __restrict__ a_dst,
                                 float* __restrict__ h, float* __restrict__ s,
                                 float* __restrict__ d, int N) {
  int wid = blockIdx.x * (blockDim.x >> 6) + (threadIdx.x >> 6);
  if (wid >= N) return;
  int lane = threadIdx.x & 63;
  const float* xr = xin + (size_t)wid * K;
  float h0 = 0.f, h1 = 0.f;
#pragma unroll
  for (int k = 0; k < K; ++k) {
    float xv = xr[k];  // wave-uniform broadcast load
    h0 = fmaf(xv, W[k * 128 + lane], h0);
    h1 = fmaf(xv, W[k * 128 + 64 + lane], h1);
  }
  h[(size_t)wid * 128 + lane] = h0;
  h[(size_t)wid * 128 + 64 + lane] = h1;
  // a_src/a_dst are [H,C] flat = 128 floats; flat index == f directly.
  float sA = h0 * a_src[lane];
  float sB = h1 * a_src[64 + lane];
  float dA = h0 * a_dst[lane];
  float dB = h1 * a_dst[64 + lane];
#pragma unroll
  for (int m = 1; m < 32; m <<= 1) {  // butterfly within 32-lane (head) groups
    sA += __shfl_xor(sA, m);
    sB += __shfl_xor(sB, m);
    dA += __shfl_xor(dA, m);
    dB += __shfl_xor(dB, m);
  }
  if ((lane & 31) == 0) {
    int hh = lane >> 5;  // 0 or 1
    s[wid * 4 + hh] = sA;
    s[wid * 4 + hh + 2] = sB;
    d[wid * 4 + hh] = dA;
    d[wid * 4 + hh + 2] = dB;
  }
}

// One wave per dst node. lane l: heads hA=l>>5 (0/1) and hA+2, channel c=l&31.
// Self-loop handled as iteration i==beg-1 with src=node.
__global__ void aggregate_kernel(const float* __restrict__ h, const float* __restrict__ s,
                                 const float* __restrict__ d, const int* __restrict__ offs,
                                 const int* __restrict__ esrc, const float* __restrict__ bias,
                                 float* __restrict__ out, int N) {
  int wid = blockIdx.x * (blockDim.x >> 6) + (threadIdx.x >> 6);
  if (wid >= N) return;
  int lane = threadIdx.x & 63;
  int hA = lane >> 5;
  float dA = d[wid * 4 + hA];
  float dB = d[wid * 4 + hA + 2];
  float acc0 = 0.f, acc1 = 0.f, den0 = 0.f, den1 = 0.f;
  int beg = offs[wid], end = offs[wid + 1];
  for (int i = beg - 1; i < end; ++i) {
    int src = (i < beg) ? wid : esrc[i];
    float s0 = s[src * 4 + hA];
    float s1 = s[src * 4 + hA + 2];
    float a0 = s0 + dA;
    a0 = (a0 > 0.f) ? a0 : 0.2f * a0;  // leaky_relu slope 0.2
    float a1 = s1 + dB;
    a1 = (a1 > 0.f) ? a1 : 0.2f * a1;
    float e0 = __expf(a0);
    float e1 = __expf(a1);
    den0 += e0;
    den1 += e1;
    const float* hr = h + (size_t)src * 128;
    acc0 = fmaf(e0, hr[lane], acc0);
    acc1 = fmaf(e1, hr[lane + 64], acc1);
  }
  float v = acc0 / den0 + acc1 / den1;  // heads {hA, hA+2} for channel c
  v += __shfl_xor(v, 32);               // add heads {1-hA, 3-hA}: all 4 heads
  v = v * 0.25f + bias[lane & 31];      // mean over heads + bias
  v = fmaxf(v, 0.f);                    // relu (applied after both GAT layers)
  if (lane < 32) out[(size_t)wid * 32 + lane] = v;
}

__global__ void node_head_kernel(const float* __restrict__ h2, const float* __restrict__ Wn,
                                 const float* __restrict__ bn, float* __restrict__ out, int N) {
  int n = blockIdx.x * blockDim.x + threadIdx.x;
  if (n >= N) return;
  float a0 = bn[0], a1 = bn[1];
  const float* hr = h2 + (size_t)n * 32;
#pragma unroll
  for (int c = 0; c < 32; ++c) {
    float v = hr[c];
    a0 = fmaf(v, Wn[c * 2], a0);
    a1 = fmaf(v, Wn[c * 2 + 1], a1);
  }
  out[n * 2] = a0;
  out[n * 2 + 1] = a1;
}

// One wave per edge-label pair: ei = [h2[a]; h2[b]] (64), z = relu(ei@We1+be1),
// out = z@We2 + be2. We1 staged in LDS.
__global__ __launch_bounds__(256) void edge_head_kernel(
    const float* __restrict__ h2, const int* __restrict__ eli, int EL,
    const float* __restrict__ We1, const float* __restrict__ be1,
    const float* __restrict__ We2, const float* __restrict__ be2, float* __restrict__ out) {
  __shared__ float w1s[64 * 64];
  for (int i = threadIdx.x; i < 64 * 64; i += blockDim.x) w1s[i] = We1[i];
  __syncthreads();
  int wid = blockIdx.x * (blockDim.x >> 6) + (threadIdx.x >> 6);
  if (wid >= EL) return;
  int lane = threadIdx.x & 63;
  int a = eli[wid];
  int b = eli[EL + wid];
  float ei = (lane < 32) ? h2[(size_t)a * 32 + lane] : h2[(size_t)b * 32 + lane - 32];
  float z = be1[lane];
#pragma unroll
  for (int k = 0; k < 64; ++k) {
    float ek = __shfl(ei, k);
    z = fmaf(ek, w1s[k * 64 + lane], z);
  }
  z = fmaxf(z, 0.f);
  float contrib = z * We2[lane];
#pragma unroll
  for (int m = 1; m < 64; m <<= 1) contrib += __shfl_xor(contrib, m);
  if (lane == 0) out[wid] = contrib + be2[0];
}

extern "C" void kernel_launch(void* const* d_in, const int* in_sizes, int n_in,
                              void* d_out, int out_size, void* d_ws, size_t ws_size,
                              hipStream_t stream) {
  const float* x = (const float*)d_in[0];
  const int* ei = (const int*)d_in[1];
  const int* eli = (const int*)d_in[2];
  const float* W1 = (const float*)d_in[3];
  const float* a_src1 = (const float*)d_in[4];
  const float* a_dst1 = (const float*)d_in[5];
  const float* b1 = (const float*)d_in[6];
  const float* W2 = (const float*)d_in[7];
  const float* a_src2 = (const float*)d_in[8];
  const float* a_dst2 = (const float*)d_in[9];
  const float* b2 = (const float*)d_in[10];
  const float* Wn = (const float*)d_in[11];
  const float* bn = (const float*)d_in[12];
  const float* We1 = (const float*)d_in[13];
  const float* be1 = (const float*)d_in[14];
  const float* We2 = (const float*)d_in[15];
  const float* be2 = (const float*)d_in[16];

  const int N = in_sizes[0] / 9;   // DIN = 9
  const int E = in_sizes[1] / 2;
  const int EL = in_sizes[2] / 2;

  // workspace layout (floats then ints)
  float* wsf = (float*)d_ws;
  float* h_full = wsf;                      // N*128
  float* sbuf = h_full + (size_t)N * 128;   // N*4
  float* dbuf = sbuf + (size_t)N * 4;       // N*4
  float* h1o = dbuf + (size_t)N * 4;        // N*32
  float* h2o = h1o + (size_t)N * 32;        // N*32
  int* offs = (int*)(h2o + (size_t)N * 32); // N+1
  int* cursor = offs + (N + 1);             // N
  int* esrc = cursor + N;                   // E

  float* out_node = (float*)d_out;          // N*2
  float* out_edge = out_node + (size_t)N * 2; // EL

  const int B = 256;
  const int wavesPerBlock = B / 64;
  int gridNwave = (N + wavesPerBlock - 1) / wavesPerBlock;

  // --- CSR build (dst-major), reused for both layers ---
  zero_int_kernel<<<(N + B - 1) / B, B, 0, stream>>>(cursor, N);
  hist_kernel<<<(E + B - 1) / B, B, 0, stream>>>(ei + E, E, cursor);
  scan_kernel<<<1, 1024, 0, stream>>>(cursor, offs, N);
  scatter_kernel<<<(E + B - 1) / B, B, 0, stream>>>(ei, ei + E, E, cursor, esrc);

  // --- layer 1 ---
  transform_kernel<9><<<gridNwave, B, 0, stream>>>(x, W1, a_src1, a_dst1, h_full, sbuf, dbuf, N);
  aggregate_kernel<<<gridNwave, B, 0, stream>>>(h_full, sbuf, dbuf, offs, esrc, b1, h1o, N);

  // --- layer 2 ---
  transform_kernel<32><<<gridNwave, B, 0, stream>>>(h1o, W2, a_src2, a_dst2, h_full, sbuf, dbuf, N);
  aggregate_kernel<<<gridNwave, B, 0, stream>>>(h_full, sbuf, dbuf, offs, esrc, b2, h2o, N);

  // --- heads ---
  node_head_kernel<<<(N + B - 1) / B, B, 0, stream>>>(h2o, Wn, bn, out_node, N);
  int gridEL = (EL + wavesPerBlock - 1) / wavesPerBlock;
  edge_head_kernel<<<gridEL, B, 0, stream>>>(h2o, eli, EL, We1, be1, We2, be2, out_edge);
}

// Round 2
// 935.892 us; speedup vs baseline: 1.4938x; 1.4938x over previous
//
#include <hip/hip_runtime.h>

// ---------------------------------------------------------------------------
// MultiTaskGNN: 2-layer GAT (H=4 heads, C=32) + node head + edge MLP head.
// Strategy: build CSR (by dst) once, then per layer:
//   transform: h = x@W (one wave/node, 2 ch/lane), s/d attention dots via shfl
//   aggregate: per dst node, single pass over incoming edges accumulating
//              Sum(exp(a)*h[src]) and Sum(exp(a)); divide at end (softmax is
//              shift-invariant; alpha is O(10) so no max pass needed).
//   edge head: one THREAD per edge; weights via wave-uniform s_load so the
//              64x64 matvec is pure VALU (R1's wave-per-edge shfl chain was
//              latency-bound at 29% VALUBusy).
// ---------------------------------------------------------------------------

__global__ void zero_int_kernel(int* p, int n) {
  int i = blockIdx.x * blockDim.x + threadIdx.x;
  if (i < n) p[i] = 0;
}

__global__ void hist_kernel(const int* __restrict__ dst, int E, int* __restrict__ cnt) {
  int i = blockIdx.x * blockDim.x + threadIdx.x;
  int stride = gridDim.x * blockDim.x;
  for (; i < E; i += stride) atomicAdd(&cnt[dst[i]], 1);
}

// Single-block exclusive scan over n counts; overwrites cnt_cursor with the
// exclusive offsets (to serve as the scatter cursor) and writes offs[0..n].
__global__ __launch_bounds__(1024) void scan_kernel(int* cnt_cursor, int* offs, int n) {
  __shared__ int wsum[16];
  __shared__ int carry;
  __shared__ int tot;
  int tid = threadIdx.x;
  int lane = tid & 63;
  int w = tid >> 6;
  if (tid == 0) carry = 0;
  __syncthreads();
  for (int base = 0; base < n; base += 1024) {
    int i = base + tid;
    int v = (i < n) ? cnt_cursor[i] : 0;
    int x = v;
#pragma unroll
    for (int d2 = 1; d2 < 64; d2 <<= 1) {
      int up = __shfl_up(x, d2);
      if (lane >= d2) x += up;
    }
    if (lane == 63) wsum[w] = x;
    __syncthreads();
    if (tid == 0) {
      int t = 0;
      for (int k = 0; k < 16; ++k) { int a = wsum[k]; wsum[k] = t; t += a; }
      tot = t;
    }
    __syncthreads();
    int excl = x - v + wsum[w] + carry;
    if (i < n) { offs[i] = excl; cnt_cursor[i] = excl; }
    __syncthreads();
    if (tid == 0) carry += tot;
    __syncthreads();
  }
  if (tid == 0) offs[n] = carry;
}

__global__ void scatter_kernel(const int* __restrict__ src, const int* __restrict__ dst, int E,
                               int* __restrict__ cursor, int* __restrict__ esrc) {
  int i = blockIdx.x * blockDim.x + threadIdx.x;
  int stride = gridDim.x * blockDim.x;
  for (; i < E; i += stride) {
    int p = atomicAdd(&cursor[dst[i]], 1);
    esrc[p] = src[i];
  }
}

// One wave per node. lane l handles flat channels f=l and f=l+64 of the 128
// (H*C) outputs. Computes h = x@W, plus s[n,h] = sum_c h*a_src, d likewise.
template <int K>
__global__ void transform_kernel(const float* __restrict__ xin, const float* __restrict__ W,
                                 const float* __restrict__ a_src, const float* __restrict__ a_dst,
                                 float* __restrict__ h, float* __restrict__ s,
                                 float* __restrict__ d, int N) {
  int wid = blockIdx.x * (blockDim.x >> 6) + (threadIdx.x >> 6);
  if (wid >= N) return;
  int lane = threadIdx.x & 63;
  const float* xr = xin + (size_t)wid * K;
  float h0 = 0.f, h1 = 0.f;
#pragma unroll
  for (int k = 0; k < K; ++k) {
    float xv = xr[k];  // wave-uniform broadcast load
    h0 = fmaf(xv, W[k * 128 + lane], h0);
    h1 = fmaf(xv, W[k * 128 + 64 + lane], h1);
  }
  h[(size_t)wid * 128 + lane] = h0;
  h[(size_t)wid * 128 + 64 + lane] = h1;
  // a_src/a_dst are [H,C] flat = 128 floats; flat index == f directly.
  float sA = h0 * a_src[lane];
  float sB = h1 * a_src[64 + lane];
  float dA = h0 * a_dst[lane];
  float dB = h1 * a_dst[64 + lane];
#pragma unroll
  for (int m = 1; m < 32; m <<= 1) {  // butterfly within 32-lane (head) groups
    sA += __shfl_xor(sA, m);
    sB += __shfl_xor(sB, m);
    dA += __shfl_xor(dA, m);
    dB += __shfl_xor(dB, m);
  }
  if ((lane & 31) == 0) {
    int hh = lane >> 5;  // 0 or 1
    s[wid * 4 + hh] = sA;
    s[wid * 4 + hh + 2] = sB;
    d[wid * 4 + hh] = dA;
    d[wid * 4 + hh + 2] = dB;
  }
}

// One wave per dst node. lane l: heads hA=l>>5 (0/1) and hA+2, channel c=l&31.
// Self-loop handled as iteration i==beg-1 with src=node.
__global__ void aggregate_kernel(const float* __restrict__ h, const float* __restrict__ s,
                                 const float* __restrict__ d, const int* __restrict__ offs,
                                 const int* __restrict__ esrc, const float* __restrict__ bias,
                                 float* __restrict__ out, int N) {
  int wid = blockIdx.x * (blockDim.x >> 6) + (threadIdx.x >> 6);
  if (wid >= N) return;
  int lane = threadIdx.x & 63;
  int hA = lane >> 5;
  float dA = d[wid * 4 + hA];
  float dB = d[wid * 4 + hA + 2];
  float acc0 = 0.f, acc1 = 0.f, den0 = 0.f, den1 = 0.f;
  int beg = offs[wid], end = offs[wid + 1];
  for (int i = beg - 1; i < end; ++i) {
    int src = (i < beg) ? wid : esrc[i];
    float s0 = s[src * 4 + hA];
    float s1 = s[src * 4 + hA + 2];
    float a0 = s0 + dA;
    a0 = (a0 > 0.f) ? a0 : 0.2f * a0;  // leaky_relu slope 0.2
    float a1 = s1 + dB;
    a1 = (a1 > 0.f) ? a1 : 0.2f * a1;
    float e0 = __expf(a0);
    float e1 = __expf(a1);
    den0 += e0;
    den1 += e1;
    const float* hr = h + (size_t)src * 128;
    acc0 = fmaf(e0, hr[lane], acc0);
    acc1 = fmaf(e1, hr[lane + 64], acc1);
  }
  float v = acc0 / den0 + acc1 / den1;  // heads {hA, hA+2} for channel c
  v += __shfl_xor(v, 32);               // add heads {1-hA, 3-hA}: all 4 heads
  v = v * 0.25f + bias[lane & 31];      // mean over heads + bias
  v = fmaxf(v, 0.f);                    // relu (applied after both GAT layers)
  if (lane < 32) out[(size_t)wid * 32 + lane] = v;
}

__global__ void node_head_kernel(const float* __restrict__ h2, const float* __restrict__ Wn,
                                 const float* __restrict__ bn, float* __restrict__ out, int N) {
  int n = blockIdx.x * blockDim.x + threadIdx.x;
  if (n >= N) return;
  float a0 = bn[0], a1 = bn[1];
  const float* hr = h2 + (size_t)n * 32;
#pragma unroll
  for (int c = 0; c < 32; ++c) {
    float v = hr[c];
    a0 = fmaf(v, Wn[c * 2], a0);
    a1 = fmaf(v, Wn[c * 2 + 1], a1);
  }
  out[n * 2] = a0;
  out[n * 2 + 1] = a1;
}

// One THREAD per edge-label pair. ei = [h2[a]; h2[b]] (64 floats in VGPRs).
// Weight addresses are wave-uniform -> scalar loads; each fma is
// v_fma_f32 vacc, vei, s_w (pure VALU, no DS). j-blocked 4x16 to bound
// unrolled code size and register pressure.
__global__ __launch_bounds__(256) void edge_head_kernel(
    const float* __restrict__ h2, const int* __restrict__ eli, int EL,
    const float* __restrict__ We1, const float* __restrict__ be1,
    const float* __restrict__ We2, const float* __restrict__ be2, float* __restrict__ out) {
  int e = blockIdx.x * blockDim.x + threadIdx.x;
  if (e >= EL) return;
  int a = eli[e];
  int b = eli[EL + e];
  const float4* ha = (const float4*)(h2 + (size_t)a * 32);
  const float4* hb = (const float4*)(h2 + (size_t)b * 32);
  float ei[64];
#pragma unroll
  for (int q = 0; q < 8; ++q) {
    float4 v = ha[q];
    ei[q * 4 + 0] = v.x; ei[q * 4 + 1] = v.y; ei[q * 4 + 2] = v.z; ei[q * 4 + 3] = v.w;
  }
#pragma unroll
  for (int q = 0; q < 8; ++q) {
    float4 v = hb[q];
    ei[32 + q * 4 + 0] = v.x; ei[32 + q * 4 + 1] = v.y; ei[32 + q * 4 + 2] = v.z; ei[32 + q * 4 + 3] = v.w;
  }
  float o = be2[0];
  for (int jb = 0; jb < 64; jb += 16) {  // dynamic: keeps code size in I$
    float acc[16];
#pragma unroll
    for (int j = 0; j < 16; ++j) acc[j] = be1[jb + j];
#pragma unroll
    for (int k = 0; k < 64; ++k) {
      float v = ei[k];
      const float* wrow = We1 + k * 64 + jb;  // wave-uniform address
#pragma unroll
      for (int j = 0; j < 16; ++j) acc[j] = fmaf(v, wrow[j], acc[j]);
    }
#pragma unroll
    for (int j = 0; j < 16; ++j) o = fmaf(fmaxf(acc[j], 0.f), We2[jb + j], o);
  }
  out[e] = o;
}

extern "C" void kernel_launch(void* const* d_in, const int* in_sizes, int n_in,
                              void* d_out, int out_size, void* d_ws, size_t ws_size,
                              hipStream_t stream) {
  const float* x = (const float*)d_in[0];
  const int* ei = (const int*)d_in[1];
  const int* eli = (const int*)d_in[2];
  const float* W1 = (const float*)d_in[3];
  const float* a_src1 = (const float*)d_in[4];
  const float* a_dst1 = (const float*)d_in[5];
  const float* b1 = (const float*)d_in[6];
  const float* W2 = (const float*)d_in[7];
  const float* a_src2 = (const float*)d_in[8];
  const float* a_dst2 = (const float*)d_in[9];
  const float* b2 = (const float*)d_in[10];
  const float* Wn = (const float*)d_in[11];
  const float* bn = (const float*)d_in[12];
  const float* We1 = (const float*)d_in[13];
  const float* be1 = (const float*)d_in[14];
  const float* We2 = (const float*)d_in[15];
  const float* be2 = (const float*)d_in[16];

  const int N = in_sizes[0] / 9;   // DIN = 9
  const int E = in_sizes[1] / 2;
  const int EL = in_sizes[2] / 2;

  // workspace layout (floats then ints)
  float* wsf = (float*)d_ws;
  float* h_full = wsf;                      // N*128
  float* sbuf = h_full + (size_t)N * 128;   // N*4
  float* dbuf = sbuf + (size_t)N * 4;       // N*4
  float* h1o = dbuf + (size_t)N * 4;        // N*32
  float* h2o = h1o + (size_t)N * 32;        // N*32
  int* offs = (int*)(h2o + (size_t)N * 32); // N+1
  int* cursor = offs + (N + 1);             // N
  int* esrc = cursor + N;                   // E

  float* out_node = (float*)d_out;          // N*2
  float* out_edge = out_node + (size_t)N * 2; // EL

  const int B = 256;
  const int wavesPerBlock = B / 64;
  int gridNwave = (N + wavesPerBlock - 1) / wavesPerBlock;

  // --- CSR build (dst-major), reused for both layers ---
  zero_int_kernel<<<(N + B - 1) / B, B, 0, stream>>>(cursor, N);
  hist_kernel<<<(E + B - 1) / B, B, 0, stream>>>(ei + E, E, cursor);
  scan_kernel<<<1, 1024, 0, stream>>>(cursor, offs, N);
  scatter_kernel<<<(E + B - 1) / B, B, 0, stream>>>(ei, ei + E, E, cursor, esrc);

  // --- layer 1 ---
  transform_kernel<9><<<gridNwave, B, 0, stream>>>(x, W1, a_src1, a_dst1, h_full, sbuf, dbuf, N);
  aggregate_kernel<<<gridNwave, B, 0, stream>>>(h_full, sbuf, dbuf, offs, esrc, b1, h1o, N);

  // --- layer 2 ---
  transform_kernel<32><<<gridNwave, B, 0, stream>>>(h1o, W2, a_src2, a_dst2, h_full, sbuf, dbuf, N);
  aggregate_kernel<<<gridNwave, B, 0, stream>>>(h_full, sbuf, dbuf, offs, esrc, b2, h2o, N);

  // --- heads ---
  node_head_kernel<<<(N + B - 1) / B, B, 0, stream>>>(h2o, Wn, bn, out_node, N);
  int gridEL = (EL + B - 1) / B;
  edge_head_kernel<<<gridEL, B, 0, stream>>>(h2o, eli, EL, We1, be1, We2, be2, out_edge);
}

// Round 3
// 830.024 us; speedup vs baseline: 1.6844x; 1.1275x over previous
//
#include <hip/hip_runtime.h>

// ---------------------------------------------------------------------------
// MultiTaskGNN: 2-layer GAT (H=4 heads, C=32) + node head + edge MLP head.
// CSR (by dst, self-loops materialized) built once; per layer:
//   transform: h = x@W (one wave/node, 2 ch/lane), s/d attention dots via shfl
//   aggregate: one wave per dst node; lane covers 4 contiguous channels
//              (float4), 32 lanes/edge, two half-waves = 2 edges/iter;
//              3-stage software pipeline over the esrc->s/h gather chain.
//              Softmax without max-pass (shift-invariant, alpha is O(10)).
//   edge head: one thread per edge; wave-uniform weight s_loads (pure VALU).
// ---------------------------------------------------------------------------

__global__ void init_int_kernel(int* p, int n, int val) {
  int i = blockIdx.x * blockDim.x + threadIdx.x;
  if (i < n) p[i] = val;
}

__global__ void hist_kernel(const int* __restrict__ dst, int E, int* __restrict__ cnt) {
  int i = blockIdx.x * blockDim.x + threadIdx.x;
  int stride = gridDim.x * blockDim.x;
  for (; i < E; i += stride) atomicAdd(&cnt[dst[i]], 1);
}

// Single-block exclusive scan over n counts; overwrites cnt_cursor with the
// exclusive offsets (to serve as the scatter cursor) and writes offs[0..n].
__global__ __launch_bounds__(1024) void scan_kernel(int* cnt_cursor, int* offs, int n) {
  __shared__ int wsum[16];
  __shared__ int carry;
  __shared__ int tot;
  int tid = threadIdx.x;
  int lane = tid & 63;
  int w = tid >> 6;
  if (tid == 0) carry = 0;
  __syncthreads();
  for (int base = 0; base < n; base += 1024) {
    int i = base + tid;
    int v = (i < n) ? cnt_cursor[i] : 0;
    int x = v;
#pragma unroll
    for (int d2 = 1; d2 < 64; d2 <<= 1) {
      int up = __shfl_up(x, d2);
      if (lane >= d2) x += up;
    }
    if (lane == 63) wsum[w] = x;
    __syncthreads();
    if (tid == 0) {
      int t = 0;
      for (int k = 0; k < 16; ++k) { int a = wsum[k]; wsum[k] = t; t += a; }
      tot = t;
    }
    __syncthreads();
    int excl = x - v + wsum[w] + carry;
    if (i < n) { offs[i] = excl; cnt_cursor[i] = excl; }
    __syncthreads();
    if (tid == 0) carry += tot;
    __syncthreads();
  }
  if (tid == 0) offs[n] = carry;
}

__global__ void scatter_kernel(const int* __restrict__ src, const int* __restrict__ dst, int E,
                               int* __restrict__ cursor, int* __restrict__ esrc) {
  int i = blockIdx.x * blockDim.x + threadIdx.x;
  int stride = gridDim.x * blockDim.x;
  for (; i < E; i += stride) {
    int p = atomicAdd(&cursor[dst[i]], 1);
    esrc[p] = src[i];
  }
}

// After scatter, cursor[i] points at the one remaining slot: the self-loop.
__global__ void selfloop_kernel(const int* __restrict__ cursor, int* __restrict__ esrc, int N) {
  int i = blockIdx.x * blockDim.x + threadIdx.x;
  if (i < N) esrc[cursor[i]] = i;
}

// One wave per node. lane l handles flat channels f=l and f=l+64 of the 128
// (H*C) outputs. Computes h = x@W, plus s[n,h] = sum_c h*a_src, d likewise.
template <int K>
__global__ void transform_kernel(const float* __restrict__ xin, const float* __restrict__ W,
                                 const float* __restrict__ a_src, const float* __restrict__ a_dst,
                                 float* __restrict__ h, float* __restrict__ s,
                                 float* __restrict__ d, int N) {
  int wid = blockIdx.x * (blockDim.x >> 6) + (threadIdx.x >> 6);
  if (wid >= N) return;
  int lane = threadIdx.x & 63;
  const float* xr = xin + (size_t)wid * K;
  float h0 = 0.f, h1 = 0.f;
#pragma unroll
  for (int k = 0; k < K; ++k) {
    float xv = xr[k];  // wave-uniform broadcast load
    h0 = fmaf(xv, W[k * 128 + lane], h0);
    h1 = fmaf(xv, W[k * 128 + 64 + lane], h1);
  }
  h[(size_t)wid * 128 + lane] = h0;
  h[(size_t)wid * 128 + 64 + lane] = h1;
  // a_src/a_dst are [H,C] flat = 128 floats; flat index == f directly.
  float sA = h0 * a_src[lane];
  float sB = h1 * a_src[64 + lane];
  float dA = h0 * a_dst[lane];
  float dB = h1 * a_dst[64 + lane];
#pragma unroll
  for (int m = 1; m < 32; m <<= 1) {  // butterfly within 32-lane (head) groups
    sA += __shfl_xor(sA, m);
    sB += __shfl_xor(sB, m);
    dA += __shfl_xor(dA, m);
    dB += __shfl_xor(dB, m);
  }
  if ((lane & 31) == 0) {
    int hh = lane >> 5;  // 0 or 1
    s[wid * 4 + hh] = sA;
    s[wid * 4 + hh + 2] = sB;
    d[wid * 4 + hh] = dA;
    d[wid * 4 + hh + 2] = dB;
  }
}

// One wave per dst node. Half-wave handles one edge stream (even/odd
// ordinals). Lane k (0..31) covers flat channels 4k..4k+3 -> head = k>>3.
// 3-stage pipeline: esrc prefetched 2 steps ahead, s/h loads 1 step ahead.
__global__ void aggregate_kernel(const float* __restrict__ h, const float* __restrict__ s,
                                 const float* __restrict__ d, const int* __restrict__ offs,
                                 const int* __restrict__ esrc, const float* __restrict__ bias,
                                 float* __restrict__ out, int N) {
  int wid = blockIdx.x * (blockDim.x >> 6) + (threadIdx.x >> 6);
  if (wid >= N) return;
  int lane = threadIdx.x & 63;
  int half = lane >> 5;
  int k = lane & 31;
  int head = k >> 3;
  float dsel = d[wid * 4 + head];
  int beg = offs[wid], end = offs[wid + 1];
  int cnt = end - beg;            // >= 1 (self-loop materialized)
  int M = (cnt + 1) >> 1;         // iterations for the longer half
  int i0 = beg + half;
  int last = end - 1;
  const float4* h4 = (const float4*)h;

  float4 acc = make_float4(0.f, 0.f, 0.f, 0.f);
  float den = 0.f;

  // prologue: step-0 loads + step-1 src
  int src_c = esrc[min(i0, last)];
  float sv_c = s[src_c * 4 + head];
  float4 hv_c = h4[(size_t)src_c * 32 + k];
  int src_n = esrc[min(i0 + 2, last)];

  for (int t = 0; t < M; ++t) {
    // issue loads for step t+1
    float sv_n = s[src_n * 4 + head];
    float4 hv_n = h4[(size_t)src_n * 32 + k];
    int src_nn = esrc[min(i0 + 2 * (t + 2), last)];
    // compute step t
    float a = sv_c + dsel;
    a = fmaxf(a, 0.2f * a);       // leaky_relu (0.2 < 1 so max works)
    float e = __expf(a);
    e = (i0 + 2 * t < end) ? e : 0.f;
    den += e;
    acc.x = fmaf(e, hv_c.x, acc.x);
    acc.y = fmaf(e, hv_c.y, acc.y);
    acc.z = fmaf(e, hv_c.z, acc.z);
    acc.w = fmaf(e, hv_c.w, acc.w);
    sv_c = sv_n; hv_c = hv_n; src_n = src_nn;
  }

  // merge the two half-wave edge streams
  acc.x += __shfl_xor(acc.x, 32);
  acc.y += __shfl_xor(acc.y, 32);
  acc.z += __shfl_xor(acc.z, 32);
  acc.w += __shfl_xor(acc.w, 32);
  den += __shfl_xor(den, 32);
  float inv = 1.f / den;
  float4 r;
  r.x = acc.x * inv; r.y = acc.y * inv; r.z = acc.z * inv; r.w = acc.w * inv;
  // mean over heads: channel block (k&7) lives at lanes k, k^8, k^16, k^24
  r.x += __shfl_xor(r.x, 8);  r.y += __shfl_xor(r.y, 8);
  r.z += __shfl_xor(r.z, 8);  r.w += __shfl_xor(r.w, 8);
  r.x += __shfl_xor(r.x, 16); r.y += __shfl_xor(r.y, 16);
  r.z += __shfl_xor(r.z, 16); r.w += __shfl_xor(r.w, 16);
  if (lane < 8) {
    float4 bv = ((const float4*)bias)[k];
    float4 o;
    o.x = fmaxf(r.x * 0.25f + bv.x, 0.f);
    o.y = fmaxf(r.y * 0.25f + bv.y, 0.f);
    o.z = fmaxf(r.z * 0.25f + bv.z, 0.f);
    o.w = fmaxf(r.w * 0.25f + bv.w, 0.f);
    ((float4*)out)[(size_t)wid * 8 + k] = o;
  }
}

__global__ void node_head_kernel(const float* __restrict__ h2, const float* __restrict__ Wn,
                                 const float* __restrict__ bn, float* __restrict__ out, int N) {
  int n = blockIdx.x * blockDim.x + threadIdx.x;
  if (n >= N) return;
  float a0 = bn[0], a1 = bn[1];
  const float* hr = h2 + (size_t)n * 32;
#pragma unroll
  for (int c = 0; c < 32; ++c) {
    float v = hr[c];
    a0 = fmaf(v, Wn[c * 2], a0);
    a1 = fmaf(v, Wn[c * 2 + 1], a1);
  }
  out[n * 2] = a0;
  out[n * 2 + 1] = a1;
}

// One THREAD per edge-label pair. ei = [h2[a]; h2[b]] (64 floats in VGPRs).
// Weight addresses are wave-uniform -> scalar loads; each fma is
// v_fma_f32 vacc, vei, s_w (pure VALU, no DS). j-blocked 4x16.
__global__ __launch_bounds__(256) void edge_head_kernel(
    const float* __restrict__ h2, const int* __restrict__ eli, int EL,
    const float* __restrict__ We1, const float* __restrict__ be1,
    const float* __restrict__ We2, const float* __restrict__ be2, float* __restrict__ out) {
  int e = blockIdx.x * blockDim.x + threadIdx.x;
  if (e >= EL) return;
  int a = eli[e];
  int b = eli[EL + e];
  const float4* ha = (const float4*)(h2 + (size_t)a * 32);
  const float4* hb = (const float4*)(h2 + (size_t)b * 32);
  float ei[64];
#pragma unroll
  for (int q = 0; q < 8; ++q) {
    float4 v = ha[q];
    ei[q * 4 + 0] = v.x; ei[q * 4 + 1] = v.y; ei[q * 4 + 2] = v.z; ei[q * 4 + 3] = v.w;
  }
#pragma unroll
  for (int q = 0; q < 8; ++q) {
    float4 v = hb[q];
    ei[32 + q * 4 + 0] = v.x; ei[32 + q * 4 + 1] = v.y; ei[32 + q * 4 + 2] = v.z; ei[32 + q * 4 + 3] = v.w;
  }
  float o = be2[0];
  for (int jb = 0; jb < 64; jb += 16) {  // dynamic: keeps code size in I$
    float acc[16];
#pragma unroll
    for (int j = 0; j < 16; ++j) acc[j] = be1[jb + j];
#pragma unroll
    for (int kk = 0; kk < 64; ++kk) {
      float v = ei[kk];
      const float* wrow = We1 + kk * 64 + jb;  // wave-uniform address
#pragma unroll
      for (int j = 0; j < 16; ++j) acc[j] = fmaf(v, wrow[j], acc[j]);
    }
#pragma unroll
    for (int j = 0; j < 16; ++j) o = fmaf(fmaxf(acc[j], 0.f), We2[jb + j], o);
  }
  out[e] = o;
}

extern "C" void kernel_launch(void* const* d_in, const int* in_sizes, int n_in,
                              void* d_out, int out_size, void* d_ws, size_t ws_size,
                              hipStream_t stream) {
  const float* x = (const float*)d_in[0];
  const int* ei = (const int*)d_in[1];
  const int* eli = (const int*)d_in[2];
  const float* W1 = (const float*)d_in[3];
  const float* a_src1 = (const float*)d_in[4];
  const float* a_dst1 = (const float*)d_in[5];
  const float* b1 = (const float*)d_in[6];
  const float* W2 = (const float*)d_in[7];
  const float* a_src2 = (const float*)d_in[8];
  const float* a_dst2 = (const float*)d_in[9];
  const float* b2 = (const float*)d_in[10];
  const float* Wn = (const float*)d_in[11];
  const float* bn = (const float*)d_in[12];
  const float* We1 = (const float*)d_in[13];
  const float* be1 = (const float*)d_in[14];
  const float* We2 = (const float*)d_in[15];
  const float* be2 = (const float*)d_in[16];

  const int N = in_sizes[0] / 9;   // DIN = 9
  const int E = in_sizes[1] / 2;
  const int EL = in_sizes[2] / 2;

  // workspace layout (floats then ints)
  float* wsf = (float*)d_ws;
  float* h_full = wsf;                      // N*128
  float* sbuf = h_full + (size_t)N * 128;   // N*4
  float* dbuf = sbuf + (size_t)N * 4;       // N*4
  float* h1o = dbuf + (size_t)N * 4;        // N*32
  float* h2o = h1o + (size_t)N * 32;        // N*32
  int* offs = (int*)(h2o + (size_t)N * 32); // N+1
  int* cursor = offs + (N + 1);             // N
  int* esrc = cursor + N;                   // E+N (self-loops included)

  float* out_node = (float*)d_out;            // N*2
  float* out_edge = out_node + (size_t)N * 2; // EL

  const int B = 256;
  const int wavesPerBlock = B / 64;
  int gridNwave = (N + wavesPerBlock - 1) / wavesPerBlock;

  // --- CSR build (dst-major, +1 slot per node for the self-loop) ---
  init_int_kernel<<<(N + B - 1) / B, B, 0, stream>>>(cursor, N, 1);
  hist_kernel<<<(E + B - 1) / B, B, 0, stream>>>(ei + E, E, cursor);
  scan_kernel<<<1, 1024, 0, stream>>>(cursor, offs, N);
  scatter_kernel<<<(E + B - 1) / B, B, 0, stream>>>(ei, ei + E, E, cursor, esrc);
  selfloop_kernel<<<(N + B - 1) / B, B, 0, stream>>>(cursor, esrc, N);

  // --- layer 1 ---
  transform_kernel<9><<<gridNwave, B, 0, stream>>>(x, W1, a_src1, a_dst1, h_full, sbuf, dbuf, N);
  aggregate_kernel<<<gridNwave, B, 0, stream>>>(h_full, sbuf, dbuf, offs, esrc, b1, h1o, N);

  // --- layer 2 ---
  transform_kernel<32><<<gridNwave, B, 0, stream>>>(h1o, W2, a_src2, a_dst2, h_full, sbuf, dbuf, N);
  aggregate_kernel<<<gridNwave, B, 0, stream>>>(h_full, sbuf, dbuf, offs, esrc, b2, h2o, N);

  // --- heads ---
  node_head_kernel<<<(N + B - 1) / B, B, 0, stream>>>(h2o, Wn, bn, out_node, N);
  int gridEL = (EL + B - 1) / B;
  edge_head_kernel<<<gridEL, B, 0, stream>>>(h2o, eli, EL, We1, be1, We2, be2, out_edge);
}